// Round 3
// baseline (777.065 us; speedup 1.0000x reference)
//
#include <hip/hip_runtime.h>
#include <hip/hip_bf16.h>

typedef __attribute__((ext_vector_type(8))) short short8;   // 8 bf16 = 4 VGPRs
typedef __attribute__((ext_vector_type(4))) float float4v;  // MFMA accumulator

#define HH 28
#define WD 28
#define CIN 64
#define COUT 128
#define KTOT 288          // K = (j*3+k)*32 + l  (l-contiguous so MFMA frags are short8)

// LDS layout (bytes)
#define VOFF  0                    // V ring: 4 slots x 30 a x 64B = 7680, XOR-swizzled
#define V0OFF 7680                 // V0 ring: 4 slots x 3 k x 64B = 768 (w=0 special column)
#define ZOFF  (V0OFF + 768)        // 64B zero slot (w>=28 lanes)
#define XOFF  (ZOFF + 64)          // raw x-row ring: 4 slots x 7168B
#define XROW  7168                 // one x row: 64 ch x 28 w x 4B
#define LDSZ  (XOFF + 4 * XROW)    // 37184 -> 4 blocks/CU

typedef const __attribute__((address_space(1))) char gchar;
typedef __attribute__((address_space(3))) char lchar;

// Wbf[i][(j*3+k)*32 + l] = bf16(W[l][j][k][i]),  W flat: ((l*3+j)*3+k)*128 + i
__global__ __launch_bounds__(256) void prep_w_kernel(const float* __restrict__ W,
                                                     __hip_bfloat16* __restrict__ Wbf) {
    int idx = blockIdx.x * 256 + threadIdx.x;
    if (idx >= COUT * KTOT) return;
    int i = idx / KTOT;
    int K = idx - i * KTOT;
    int jk = K >> 5;
    int l = K & 31;
    int j = jk / 3;
    int k = jk - j * 3;
    Wbf[idx] = __float2bfloat16(W[((l * 3 + j) * 3 + k) * COUT + i]);
}

// One block per image m. 256 threads = 4 waves. Rolling-row software pipeline:
// iter h: [wave3: stage x row r=h+4 via global_load_lds] [build V row rp=h+3 from LDS x]
//         [all: MFMA compute h] [barrier] [stores h].
__global__ __launch_bounds__(256, 4) void conv_kernel(const float* __restrict__ x,
                                                      const __hip_bfloat16* __restrict__ Wbf,
                                                      float* __restrict__ out) {
    __shared__ __align__(16) char L[LDSZ];
    char* Lb = (char*)L;

    const int m = blockIdx.x;
    const int tid = threadIdx.x;
    const float* xm = x + (size_t)m * (CIN * HH * WD);

    const int lane = tid & 63;
    const int wv = tid >> 6;            // wave -> i-base = wv*32
    const int wrow = lane & 15;
    const int q = lane >> 4;
    const unsigned qb = (unsigned)q * 16;

    if (tid < 16) *(float*)(Lb + ZOFF + tid * 4) = 0.f;   // zero slot

    // ---- A fragments: load once, pin resident via asm (prevents per-h L2 re-reads)
    short8 Areg[2][9];
#pragma unroll
    for (int mt = 0; mt < 2; ++mt) {
        const __hip_bfloat16* ap = Wbf + (wv * 32 + mt * 16 + wrow) * KTOT + q * 8;
#pragma unroll
        for (int s = 0; s < 9; ++s)
            Areg[mt][s] = *(const short8*)(ap + s * 32);
    }

    // stage raw x row r into x-ring slot r&3 (wave 3 only; 7 x global_load_lds dwordx4)
    auto stage_row = [&](int r) {
        if (wv == 3 && r < HH) {
            char* dst = Lb + XOFF + (unsigned)(r & 3) * XROW;
#pragma unroll
            for (int t = 0; t < 7; ++t) {
                int fi = t * 256 + lane * 4;        // float index over [ch][w], w minor
                int ch = fi / 28;
                int w = fi - ch * 28;
                const float* gsrc = xm + (ch * HH + r) * WD + w;
                __builtin_amdgcn_global_load_lds((gchar*)(const char*)gsrc,
                                                 (lchar*)(dst + t * 1024), 16, 0, 0);
            }
        }
    };

    // build V row rp (and V0 column) from LDS-resident x row r=rp-1
    // V[l][r][a] = [a<28]*x[l][r][(a-1)%28] + [1<=a<=28]*x[l+32][r][(a-2)%28]
    auto build_row = [&](int rp) {
        int r = rp - 1;
        bool rok = (r >= 0) && (r < HH);
        unsigned xbase = XOFF + (unsigned)(r & 3) * XROW;
        const float* xr = (const float*)(Lb + xbase);
        if (tid < 128) {
            int a = tid & 31;
            int lq = tid >> 5;
            bool m1 = rok && (a < 28);
            bool m2 = rok && (a >= 1) && (a <= 28);
            int i1 = a - 1; if (i1 < 0) i1 += 28;   // (a-1) mod 28
            int i2 = a - 2; if (i2 < 0) i2 += 28;   // (a-2) mod 28
            short8 sv;
#pragma unroll
            for (int c = 0; c < 8; ++c) {
                int ch = lq * 8 + c;
                float t1 = m1 ? xr[ch * WD + i1] : 0.f;
                float t2 = m2 ? xr[(ch + 32) * WD + i2] : 0.f;
                __hip_bfloat16 hv = __float2bfloat16(t1 + t2);
                sv[c] = *reinterpret_cast<short*>(&hv);
            }
            if (a < 30) {
                unsigned byte = (unsigned)((((rp & 3) * 30 + a) * 64) + lq * 16);
                byte ^= (byte >> 3) & 0x30;         // bank swizzle (write == read formula)
                *(short8*)(Lb + byte) = sv;
            }
        } else if (tid < 192) {
            // V0: w=0 special column. k=0: x2[25]; k=1: x1[27]+x2[26]; k=2: x1[0]
#pragma unroll
            for (int e0 = 0; e0 < 2; ++e0) {
                int e = (tid - 128) + e0 * 64;
                if (e < 96) {
                    int k = e >> 5;
                    int l = e & 31;
                    float v = 0.f;
                    if (rok) {
                        if (k == 0) v = xr[(l + 32) * WD + 25];
                        else if (k == 1) v = xr[l * WD + 27] + xr[(l + 32) * WD + 26];
                        else v = xr[l * WD + 0];
                    }
                    __hip_bfloat16 hv = __float2bfloat16(v);
                    *(__hip_bfloat16*)(Lb + V0OFF +
                        (unsigned)((((rp & 3) * 3 + k) * 64) + l * 2)) = hv;
                }
            }
        }
    };

    // ---- prologue: stage x rows 0..3, build V rows 0..2
    stage_row(0); stage_row(1); stage_row(2); stage_row(3);
    if (wv == 3) asm volatile("s_waitcnt vmcnt(0)" ::: "memory");
    __syncthreads();
    build_row(0); build_row(1); build_row(2);
    __syncthreads();

    // pin A fragments in registers at this point (no rematerialization into the loop)
    asm volatile(""
        : "+v"(Areg[0][0]), "+v"(Areg[0][1]), "+v"(Areg[0][2]), "+v"(Areg[0][3]),
          "+v"(Areg[0][4]), "+v"(Areg[0][5]), "+v"(Areg[0][6]), "+v"(Areg[0][7]),
          "+v"(Areg[0][8]),
          "+v"(Areg[1][0]), "+v"(Areg[1][1]), "+v"(Areg[1][2]), "+v"(Areg[1][3]),
          "+v"(Areg[1][4]), "+v"(Areg[1][5]), "+v"(Areg[1][6]), "+v"(Areg[1][7]),
          "+v"(Areg[1][8]));

    const bool spec0 = (wrow == 0);     // nt=0: w==0 -> V0 column
    const bool spec1 = (wrow >= 12);    // nt=1: w>=28 -> zero slot

    for (int h = 0; h < HH; ++h) {
        stage_row(h + 4);               // x row for build at iter h+2
        if (h <= 26) build_row(h + 3);  // V row for compute at iters h+1..h+3

        float4v acc[2][2] = {};
#pragma unroll
        for (int s = 0; s < 9; ++s) {
            const int j = s / 3;
            const int k = s - j * 3;
            const unsigned slot = (unsigned)((h + j) & 3);
            int a0 = wrow + k - 1;
            unsigned b0 = (unsigned)(((int)(slot * 30) + a0) * 64) + qb;
            b0 ^= (b0 >> 3) & 0x30;
            unsigned off0 = spec0 ? (unsigned)(V0OFF + (slot * 3 + k) * 64) + qb : b0;
            unsigned b1 = (unsigned)((slot * 30 + (unsigned)(wrow + 15 + k)) * 64) + qb;
            b1 ^= (b1 >> 3) & 0x30;
            unsigned off1 = spec1 ? (unsigned)ZOFF + qb : b1;

            short8 bfr0 = *(const short8*)(Lb + off0);   // ds_read_b128
            short8 bfr1 = *(const short8*)(Lb + off1);

            acc[0][0] = __builtin_amdgcn_mfma_f32_16x16x32_bf16(Areg[0][s], bfr0, acc[0][0], 0, 0, 0);
            acc[1][0] = __builtin_amdgcn_mfma_f32_16x16x32_bf16(Areg[1][s], bfr0, acc[1][0], 0, 0, 0);
            acc[0][1] = __builtin_amdgcn_mfma_f32_16x16x32_bf16(Areg[0][s], bfr1, acc[0][1], 0, 0, 0);
            acc[1][1] = __builtin_amdgcn_mfma_f32_16x16x32_bf16(Areg[1][s], bfr1, acc[1][1], 0, 0, 0);
        }

        if (wv == 3) asm volatile("s_waitcnt vmcnt(0)" ::: "memory");
        __syncthreads();

        // stores after the barrier: they drain during the NEXT iteration
#pragma unroll
        for (int mt = 0; mt < 2; ++mt) {
            const int ibase = wv * 32 + mt * 16 + q * 4;
            float* op0 = out + (((size_t)m * COUT + ibase) * HH + h) * WD;
#pragma unroll
            for (int rr = 0; rr < 4; ++rr) {
                op0[rr * (HH * WD) + wrow] = acc[mt][0][rr];
                if (wrow < 12) op0[rr * (HH * WD) + 16 + wrow] = acc[mt][1][rr];
            }
        }
    }
}

extern "C" void kernel_launch(void* const* d_in, const int* in_sizes, int n_in,
                              void* d_out, int out_size, void* d_ws, size_t ws_size,
                              hipStream_t stream) {
    const float* x = (const float*)d_in[0];   // (1024, 64, 28, 28) fp32
    const float* W = (const float*)d_in[1];   // (32, 3, 3, 128) fp32
    float* out = (float*)d_out;               // (1024, 128, 28, 28) fp32
    __hip_bfloat16* Wbf = (__hip_bfloat16*)d_ws;  // 128*288 bf16 = 73728 B

    prep_w_kernel<<<(COUT * KTOT + 255) / 256, 256, 0, stream>>>(W, Wbf);
    conv_kernel<<<1024, 256, 0, stream>>>(x, Wbf, out);
}